// Round 6
// baseline (1897.972 us; speedup 1.0000x reference)
//
#include <hip/hip_runtime.h>
#include <cstdint>

#define N_PTS   8192
#define N_BATCH 8
#define NPOINT  2048
#define NSAMPLE 32
#define C_FEAT  64
#define R2      0.04f
#define FPS_T   512
#define CH      16          // points per thread = one chunk
#define NBINS   512         // 9-bit morton (3 bits/axis)

static __device__ __forceinline__ uint32_t spread3(uint32_t v) {
  return (v & 1u) | ((v & 2u) << 2) | ((v & 4u) << 4);
}

static __device__ __forceinline__ uint32_t cell_of(float x, float y, float z) {
  int ix = (int)(x * 8.0f); ix = ix < 0 ? 0 : (ix > 7 ? 7 : ix);
  int iy = (int)(y * 8.0f); iy = iy < 0 ? 0 : (iy > 7 ? 7 : iy);
  int iz = (int)(z * 8.0f); iz = iz < 0 ? 0 : (iz > 7 ? 7 : iz);
  return spread3((uint32_t)ix) | (spread3((uint32_t)iy) << 1) | (spread3((uint32_t)iz) << 2);
}

// Wave-max step on packed positive f64 key via DPP (validated R2/R3, absmax 0).
#define DPP_MAXD(v, CTRL) do {                                                          \
  uint64_t u_ = __builtin_bit_cast(uint64_t, v);                                        \
  int lo_ = __builtin_amdgcn_update_dpp(0, (int)(uint32_t)u_,         CTRL, 0xF, 0xF, true); \
  int hi_ = __builtin_amdgcn_update_dpp(0, (int)(uint32_t)(u_ >> 32), CTRL, 0xF, 0xF, true); \
  double p_ = __builtin_bit_cast(double, ((uint64_t)(uint32_t)hi_ << 32) | (uint64_t)(uint32_t)lo_); \
  v = __builtin_fmax(v, p_);                                                            \
} while (0)

// ---------------------------------------------------------------------------
// FPS, one block per batch. R3's verified skeleton verbatim; ONLY the chunk
// state changed: per-point f64 key (d2bits<<32)|~idx.
//   update    = __builtin_fmin(key, cand)  [same low bits -> compares d2;
//               u64 order == f64 order for positive doubles]
//   chunk max = __builtin_fmax tree         [R3-proven primitive on these keys;
//               ties -> larger ~idx = smaller idx = first occurrence]
// All coordinate arithmetic is SCALAR, exact R3 op order: ((dx*dx+dy*dy)+dz*dz),
// contract off. No vector types (bisects out R4/R5's f2 math).
// ---------------------------------------------------------------------------
__global__ __launch_bounds__(FPS_T) void fps_kernel(const float* __restrict__ xyz,
                                                    float* __restrict__ new_xyz) {
  __shared__ float sx[N_PTS], sy[N_PTS], sz[N_PTS];
  __shared__ int perm[N_PTS];          // setup only; reused as cent[] in loop
  __shared__ uint32_t bins[NBINS];
  __shared__ double pkey[2][FPS_T / 64];
  float* cent = (float*)perm;          // [NPOINT*3] = 24 KB < 32 KB

  const int b = blockIdx.x;
  const int t = threadIdx.x;
  const int lane = t & 63;
  const int w = t >> 6;
  const float* xb = xyz + (size_t)b * N_PTS * 3;

  // ---- setup: stage coords ----
  for (int e = t; e < N_PTS * 3; e += FPS_T) {
    float v = xb[e];
    int p = e / 3, c = e - 3 * p;
    if (c == 0) sx[p] = v;
    else if (c == 1) sy[p] = v;
    else sz[p] = v;
  }
  bins[t] = 0;            // FPS_T == NBINS
  __syncthreads();

  // ---- counting sort by morton cell: histogram ----
#pragma unroll
  for (int k = 0; k < CH; ++k) {
    int p = k * FPS_T + t;
    atomicAdd(&bins[cell_of(sx[p], sy[p], sz[p])], 1u);
  }
  __syncthreads();

  // ---- exclusive scan of 512 bins (wave 0, in place) ----
  if (t < 64) {
    uint32_t v[8], e[8], run = 0;
#pragma unroll
    for (int j = 0; j < 8; ++j) v[j] = bins[t * 8 + j];
#pragma unroll
    for (int j = 0; j < 8; ++j) { e[j] = run; run += v[j]; }
    uint32_t inc = run;
#pragma unroll
    for (int off = 1; off < 64; off <<= 1) {
      uint32_t o = __shfl_up(inc, off, 64);
      if (t >= off) inc += o;
    }
    uint32_t base = inc - run;
#pragma unroll
    for (int j = 0; j < 8; ++j) bins[t * 8 + j] = base + e[j];
  }
  __syncthreads();

  // ---- scatter permutation ----
#pragma unroll
  for (int k = 0; k < CH; ++k) {
    int p = k * FPS_T + t;
    uint32_t pos = atomicAdd(&bins[cell_of(sx[p], sy[p], sz[p])], 1u);
    perm[pos] = p;
  }
  __syncthreads();

  // ---- load chunk into registers (scalar, R3-style), init keys, bbox ----
  float rx[CH], ry[CH], rz[CH];
  double keys[CH];
#pragma unroll
  for (int j = 0; j < CH; ++j) {
    int p = perm[CH * t + j];
    rx[j] = sx[p]; ry[j] = sy[p]; rz[j] = sz[p];
    keys[j] = __builtin_bit_cast(double,
        ((uint64_t)0x7F800000u << 32) | (uint64_t)(0xFFFFFFFFu - (uint32_t)p));
  }
  float bnx = rx[0], bxx = rx[0], bny = ry[0], bxy = ry[0], bnz = rz[0], bxz = rz[0];
#pragma unroll
  for (int j = 1; j < CH; ++j) {
    bnx = fminf(bnx, rx[j]); bxx = fmaxf(bxx, rx[j]);
    bny = fminf(bny, ry[j]); bxy = fmaxf(bxy, ry[j]);
    bnz = fminf(bnz, rz[j]); bxz = fmaxf(bxz, rz[j]);
  }
  __syncthreads();   // perm fully consumed; cent alias is now safe

  // cached chunk max key (+inf dist -> everyone active at it=0)
  double ck = __builtin_bit_cast(double, ((uint64_t)0x7F800000u << 32) | 0xFFFFFFFFull);
  int far = 0;

  for (int it = 0; it < NPOINT; ++it) {
    float cx = sx[far], cy = sy[far], cz = sz[far];
    if (t == 0) {   // LDS staging only -- no global store in the loop
      cent[it * 3 + 0] = cx;
      cent[it * 3 + 1] = cy;
      cent[it * 3 + 2] = cz;
    }

    // conservative lower bound of any d2 in this chunk (margin 1e-5 >> fp err)
    float gx = fmaxf(fmaxf(bnx - cx, cx - bxx), 0.0f);
    float gy = fmaxf(fmaxf(bny - cy, cy - bxy), 0.0f);
    float gz = fmaxf(fmaxf(bnz - cz, cz - bxz), 0.0f);
    float lb = gx * gx + gy * gy + gz * gz;
    float cdist = __builtin_bit_cast(float, (uint32_t)(__builtin_bit_cast(uint64_t, ck) >> 32));

    if (!(lb * 0.99999f >= cdist)) {
      {
#pragma clang fp contract(off)
#pragma unroll
        for (int j = 0; j < CH; ++j) {
          float dx = rx[j] - cx;
          float a = dx * dx;
          float dy = ry[j] - cy;
          a = a + dy * dy;           // exact left-to-right, no FMA (R3-identical)
          float dz = rz[j] - cz;
          a = a + dz * dz;
          uint64_t kj = __builtin_bit_cast(uint64_t, keys[j]);
          double cand = __builtin_bit_cast(double,
              ((uint64_t)__builtin_bit_cast(uint32_t, a) << 32) | (kj & 0xFFFFFFFFull));
          keys[j] = __builtin_fmin(keys[j], cand);
        }
      }
      // chunk max (f64 tree: dist major, ~idx minor -> first-occurrence ties)
      double m0 = __builtin_fmax(keys[0], keys[1]);
      double m1 = __builtin_fmax(keys[2], keys[3]);
      double m2 = __builtin_fmax(keys[4], keys[5]);
      double m3 = __builtin_fmax(keys[6], keys[7]);
      double m4 = __builtin_fmax(keys[8], keys[9]);
      double m5 = __builtin_fmax(keys[10], keys[11]);
      double m6 = __builtin_fmax(keys[12], keys[13]);
      double m7 = __builtin_fmax(keys[14], keys[15]);
      m0 = __builtin_fmax(m0, m1); m2 = __builtin_fmax(m2, m3);
      m4 = __builtin_fmax(m4, m5); m6 = __builtin_fmax(m6, m7);
      ck = __builtin_fmax(__builtin_fmax(m0, m2), __builtin_fmax(m4, m6));
    }

    // wave reduce (all waves, every iteration -- R3-verified structure)
    double key = ck;
    DPP_MAXD(key, 0x111);   // row_shr 1
    DPP_MAXD(key, 0x112);   // row_shr 2
    DPP_MAXD(key, 0x114);   // row_shr 4
    DPP_MAXD(key, 0x118);   // row_shr 8
    DPP_MAXD(key, 0x142);   // row_bcast 15
    DPP_MAXD(key, 0x143);   // row_bcast 31  -> lane 63 has wave max
    if (lane == 63) pkey[it & 1][w] = key;
    __syncthreads();

    const double* pk = pkey[it & 1];
    double g01 = __builtin_fmax(pk[0], pk[1]);
    double g23 = __builtin_fmax(pk[2], pk[3]);
    double g45 = __builtin_fmax(pk[4], pk[5]);
    double g67 = __builtin_fmax(pk[6], pk[7]);
    double g = __builtin_fmax(__builtin_fmax(g01, g23), __builtin_fmax(g45, g67));
    far = (int)(0xFFFFFFFFu - (uint32_t)__builtin_bit_cast(uint64_t, g));
  }

  // ---- one-time coalesced copy-out of staged centroids ----
  __syncthreads();
  float* ob = new_xyz + (size_t)b * NPOINT * 3;
  for (int e = t; e < NPOINT * 3; e += FPS_T) ob[e] = cent[e];
}

// ---------------------------------------------------------------------------
// Ball query + gather + concat, one wave per query (unchanged, verified).
// ---------------------------------------------------------------------------
__global__ __launch_bounds__(256) void ball_group_kernel(const float* __restrict__ xyz,
                                                         const float* __restrict__ points,
                                                         const float* __restrict__ new_xyz,
                                                         float* __restrict__ out_np) {
  __shared__ int list[4][NSAMPLE];
  const int wslot = threadIdx.x >> 6;
  const int lane = threadIdx.x & 63;
  const int qg = blockIdx.x * 4 + wslot;
  const int b = qg >> 11;

  const float* xb = xyz + (size_t)b * N_PTS * 3;
  const float* nq = new_xyz + (size_t)qg * 3;
  const float cqx = nq[0], cqy = nq[1], cqz = nq[2];

  int K = 0;
  {
#pragma clang fp contract(off)
    for (int c = 0; c < N_PTS / 64; ++c) {
      const int pt = c * 64 + lane;
      const float* p = xb + pt * 3;
      float dx = cqx - p[0];
      float dy = cqy - p[1];
      float dz = cqz - p[2];
      float d2 = dx * dx;
      d2 = d2 + dy * dy;
      d2 = d2 + dz * dz;
      bool in = d2 < R2;
      unsigned long long mask = __ballot(in);
      if (in) {
        int rank = __builtin_amdgcn_mbcnt_hi((uint32_t)(mask >> 32),
                     __builtin_amdgcn_mbcnt_lo((uint32_t)mask, 0));
        int s = K + rank;
        if (s < NSAMPLE) list[wslot][s] = pt;
      }
      K += (int)__popcll(mask);
      if (K >= NSAMPLE) break;   // wave-uniform
    }
  }
  __builtin_amdgcn_wave_barrier();
  int Kc = K < NSAMPLE ? K : NSAMPLE;
  int first = list[wslot][0];
  if (lane >= Kc && lane < NSAMPLE) list[wslot][lane] = first;
  __builtin_amdgcn_wave_barrier();

  const float* pb = points + (size_t)b * N_PTS * C_FEAT;
  float* oq = out_np + (size_t)qg * (NSAMPLE * 67);
  for (int r = 0; r < 34; ++r) {
    int tt = r * 64 + lane;
    if (tt < NSAMPLE * 67) {
      int s = tt / 67;
      int f = tt - s * 67;
      int idx = list[wslot][s];
      float val;
      if (f < 3) {
        float cf = (f == 0) ? cqx : ((f == 1) ? cqy : cqz);
        val = xb[idx * 3 + f] - cf;
      } else {
        val = pb[(size_t)idx * C_FEAT + (f - 3)];
      }
      oq[tt] = val;
    }
  }
}

extern "C" void kernel_launch(void* const* d_in, const int* in_sizes, int n_in,
                              void* d_out, int out_size, void* d_ws, size_t ws_size,
                              hipStream_t stream) {
  const float* xyz = (const float*)d_in[0];
  const float* points = (const float*)d_in[1];
  float* out = (float*)d_out;
  float* new_xyz = out;
  float* new_points = out + (size_t)N_BATCH * NPOINT * 3;

  fps_kernel<<<N_BATCH, FPS_T, 0, stream>>>(xyz, new_xyz);
  ball_group_kernel<<<(N_BATCH * NPOINT) / 4, 256, 0, stream>>>(xyz, points, new_xyz, new_points);
}

// Round 7
// 1683.222 us; speedup vs baseline: 1.1276x; 1.1276x over previous
//
#include <hip/hip_runtime.h>
#include <cstdint>

#define N_PTS   8192
#define N_BATCH 8
#define NPOINT  2048
#define NSAMPLE 32
#define C_FEAT  64
#define R2      0.04f
#define FPS_T   1024
#define CH      (N_PTS / FPS_T)   // 8 points per thread = one chunk
#define NBINS   512               // 9-bit morton (3 bits/axis)
#define NWAVE   (FPS_T / 64)      // 16

static __device__ __forceinline__ uint32_t spread3(uint32_t v) {
  return (v & 1u) | ((v & 2u) << 2) | ((v & 4u) << 4);
}

static __device__ __forceinline__ uint32_t cell_of(float x, float y, float z) {
  int ix = (int)(x * 8.0f); ix = ix < 0 ? 0 : (ix > 7 ? 7 : ix);
  int iy = (int)(y * 8.0f); iy = iy < 0 ? 0 : (iy > 7 ? 7 : iy);
  int iz = (int)(z * 8.0f); iz = iz < 0 ? 0 : (iz > 7 ? 7 : iz);
  return spread3((uint32_t)ix) | (spread3((uint32_t)iy) << 1) | (spread3((uint32_t)iz) << 2);
}

// Wave-max step on packed positive f64 key via DPP (validated R2/R3/R6).
#define DPP_MAXD(v, CTRL) do {                                                          \
  uint64_t u_ = __builtin_bit_cast(uint64_t, v);                                        \
  int lo_ = __builtin_amdgcn_update_dpp(0, (int)(uint32_t)u_,         CTRL, 0xF, 0xF, true); \
  int hi_ = __builtin_amdgcn_update_dpp(0, (int)(uint32_t)(u_ >> 32), CTRL, 0xF, 0xF, true); \
  double p_ = __builtin_bit_cast(double, ((uint64_t)(uint32_t)hi_ << 32) | (uint64_t)(uint32_t)lo_); \
  v = __builtin_fmax(v, p_);                                                            \
} while (0)

// ---------------------------------------------------------------------------
// FPS, one block per batch. R3's verified structure verbatim (f32 dist state,
// fmax tree + first-occurrence tie scan, DPP f64 key reduce, lane-63 slots,
// scalar cross-wave tree, sx[far] read, exact bbox pruning). Only parameter
// change vs R3: 1024 threads, 8-point chunks -> straggler update halves.
// ---------------------------------------------------------------------------
__global__ __launch_bounds__(FPS_T) void fps_kernel(const float* __restrict__ xyz,
                                                    float* __restrict__ new_xyz) {
  __shared__ float sx[N_PTS], sy[N_PTS], sz[N_PTS];
  __shared__ int perm[N_PTS];          // setup only; reused as cent[] in loop
  __shared__ uint32_t bins[NBINS];
  __shared__ double pkey[2][NWAVE];
  float* cent = (float*)perm;          // [NPOINT*3] = 24 KB < 32 KB

  const int b = blockIdx.x;
  const int t = threadIdx.x;
  const int lane = t & 63;
  const int w = t >> 6;
  const float* xb = xyz + (size_t)b * N_PTS * 3;

  // ---- setup: stage coords ----
  for (int e = t; e < N_PTS * 3; e += FPS_T) {
    float v = xb[e];
    int p = e / 3, c = e - 3 * p;
    if (c == 0) sx[p] = v;
    else if (c == 1) sy[p] = v;
    else sz[p] = v;
  }
  if (t < NBINS) bins[t] = 0;
  __syncthreads();

  // ---- counting sort by morton cell: histogram ----
#pragma unroll
  for (int k = 0; k < CH; ++k) {
    int p = k * FPS_T + t;
    atomicAdd(&bins[cell_of(sx[p], sy[p], sz[p])], 1u);
  }
  __syncthreads();

  // ---- exclusive scan of 512 bins (wave 0, in place) ----
  if (t < 64) {
    uint32_t v[8], e[8], run = 0;
#pragma unroll
    for (int j = 0; j < 8; ++j) v[j] = bins[t * 8 + j];
#pragma unroll
    for (int j = 0; j < 8; ++j) { e[j] = run; run += v[j]; }
    uint32_t inc = run;
#pragma unroll
    for (int off = 1; off < 64; off <<= 1) {
      uint32_t o = __shfl_up(inc, off, 64);
      if (t >= off) inc += o;
    }
    uint32_t base = inc - run;
#pragma unroll
    for (int j = 0; j < 8; ++j) bins[t * 8 + j] = base + e[j];
  }
  __syncthreads();

  // ---- scatter permutation ----
#pragma unroll
  for (int k = 0; k < CH; ++k) {
    int p = k * FPS_T + t;
    uint32_t pos = atomicAdd(&bins[cell_of(sx[p], sy[p], sz[p])], 1u);
    perm[pos] = p;
  }
  __syncthreads();

  // ---- load chunk into registers, compute bbox ----
  float rx[CH], ry[CH], rz[CH], dist[CH];
  uint32_t ridx[CH];
#pragma unroll
  for (int j = 0; j < CH; ++j) {
    int p = perm[CH * t + j];
    ridx[j] = (uint32_t)p;
    rx[j] = sx[p]; ry[j] = sy[p]; rz[j] = sz[p];
    dist[j] = __builtin_inff();
  }
  float bnx = rx[0], bxx = rx[0], bny = ry[0], bxy = ry[0], bnz = rz[0], bxz = rz[0];
#pragma unroll
  for (int j = 1; j < CH; ++j) {
    bnx = fminf(bnx, rx[j]); bxx = fmaxf(bxx, rx[j]);
    bny = fminf(bny, ry[j]); bxy = fmaxf(bxy, ry[j]);
    bnz = fminf(bnz, rz[j]); bxz = fmaxf(bxz, rz[j]);
  }
  __syncthreads();   // perm fully consumed; cent alias is now safe

  float cmax = __builtin_inff();   // chunk max dist (cached)
  uint32_t cidx = 0;               // chunk argmax orig idx (cached)
  int far = 0;

  for (int it = 0; it < NPOINT; ++it) {
    float cx = sx[far], cy = sy[far], cz = sz[far];
    if (t == 0) {   // LDS staging only -- no global store in the loop
      cent[it * 3 + 0] = cx;
      cent[it * 3 + 1] = cy;
      cent[it * 3 + 2] = cz;
    }

    // conservative lower bound of any d2 in this chunk (margin 1e-5 >> fp err)
    float gx = fmaxf(fmaxf(bnx - cx, cx - bxx), 0.0f);
    float gy = fmaxf(fmaxf(bny - cy, cy - bxy), 0.0f);
    float gz = fmaxf(fmaxf(bnz - cz, cz - bxz), 0.0f);
    float lb = gx * gx + gy * gy + gz * gz;

    if (!(lb * 0.99999f >= cmax)) {
      {
#pragma clang fp contract(off)
#pragma unroll
        for (int j = 0; j < CH; ++j) {
          float dx = rx[j] - cx;
          float a = dx * dx;
          float dy = ry[j] - cy;
          a = a + dy * dy;           // exact left-to-right, no FMA
          float dz = rz[j] - cz;
          a = a + dz * dz;
          dist[j] = fminf(dist[j], a);
        }
      }
      // chunk max (tree) + first-occurrence (min orig idx) tie resolution
      float m0 = fmaxf(dist[0], dist[1]), m1 = fmaxf(dist[2], dist[3]);
      float m2 = fmaxf(dist[4], dist[5]), m3 = fmaxf(dist[6], dist[7]);
      cmax = fmaxf(fmaxf(m0, m1), fmaxf(m2, m3));
      uint32_t mi = 0xFFFFFFFFu;
#pragma unroll
      for (int j = 0; j < CH; ++j) {
        uint32_t cand = ridx[j] < mi ? ridx[j] : mi;
        mi = (dist[j] == cmax) ? cand : mi;
      }
      cidx = mi;
    }

    double key = __builtin_bit_cast(double,
        ((uint64_t)__builtin_bit_cast(uint32_t, cmax) << 32) |
        (uint64_t)(0xFFFFFFFFu - cidx));

    DPP_MAXD(key, 0x111);   // row_shr 1
    DPP_MAXD(key, 0x112);   // row_shr 2
    DPP_MAXD(key, 0x114);   // row_shr 4
    DPP_MAXD(key, 0x118);   // row_shr 8
    DPP_MAXD(key, 0x142);   // row_bcast 15
    DPP_MAXD(key, 0x143);   // row_bcast 31  -> lane 63 has wave max
    if (lane == 63) pkey[it & 1][w] = key;
    __syncthreads();

    const double* pk = pkey[it & 1];
    double g0 = __builtin_fmax(pk[0], pk[1]);
    double g1 = __builtin_fmax(pk[2], pk[3]);
    double g2 = __builtin_fmax(pk[4], pk[5]);
    double g3 = __builtin_fmax(pk[6], pk[7]);
    double g4 = __builtin_fmax(pk[8], pk[9]);
    double g5 = __builtin_fmax(pk[10], pk[11]);
    double g6 = __builtin_fmax(pk[12], pk[13]);
    double g7 = __builtin_fmax(pk[14], pk[15]);
    g0 = __builtin_fmax(g0, g1); g2 = __builtin_fmax(g2, g3);
    g4 = __builtin_fmax(g4, g5); g6 = __builtin_fmax(g6, g7);
    double g = __builtin_fmax(__builtin_fmax(g0, g2), __builtin_fmax(g4, g6));
    far = (int)(0xFFFFFFFFu - (uint32_t)__builtin_bit_cast(uint64_t, g));
  }

  // ---- one-time coalesced copy-out of staged centroids ----
  __syncthreads();
  float* ob = new_xyz + (size_t)b * NPOINT * 3;
  for (int e = t; e < NPOINT * 3; e += FPS_T) ob[e] = cent[e];
}

// ---------------------------------------------------------------------------
// Ball query + gather + concat, one wave per query (unchanged, verified).
// ---------------------------------------------------------------------------
__global__ __launch_bounds__(256) void ball_group_kernel(const float* __restrict__ xyz,
                                                         const float* __restrict__ points,
                                                         const float* __restrict__ new_xyz,
                                                         float* __restrict__ out_np) {
  __shared__ int list[4][NSAMPLE];
  const int wslot = threadIdx.x >> 6;
  const int lane = threadIdx.x & 63;
  const int qg = blockIdx.x * 4 + wslot;
  const int b = qg >> 11;

  const float* xb = xyz + (size_t)b * N_PTS * 3;
  const float* nq = new_xyz + (size_t)qg * 3;
  const float cqx = nq[0], cqy = nq[1], cqz = nq[2];

  int K = 0;
  {
#pragma clang fp contract(off)
    for (int c = 0; c < N_PTS / 64; ++c) {
      const int pt = c * 64 + lane;
      const float* p = xb + pt * 3;
      float dx = cqx - p[0];
      float dy = cqy - p[1];
      float dz = cqz - p[2];
      float d2 = dx * dx;
      d2 = d2 + dy * dy;
      d2 = d2 + dz * dz;
      bool in = d2 < R2;
      unsigned long long mask = __ballot(in);
      if (in) {
        int rank = __builtin_amdgcn_mbcnt_hi((uint32_t)(mask >> 32),
                     __builtin_amdgcn_mbcnt_lo((uint32_t)mask, 0));
        int s = K + rank;
        if (s < NSAMPLE) list[wslot][s] = pt;
      }
      K += (int)__popcll(mask);
      if (K >= NSAMPLE) break;   // wave-uniform
    }
  }
  __builtin_amdgcn_wave_barrier();
  int Kc = K < NSAMPLE ? K : NSAMPLE;
  int first = list[wslot][0];
  if (lane >= Kc && lane < NSAMPLE) list[wslot][lane] = first;
  __builtin_amdgcn_wave_barrier();

  const float* pb = points + (size_t)b * N_PTS * C_FEAT;
  float* oq = out_np + (size_t)qg * (NSAMPLE * 67);
  for (int r = 0; r < 34; ++r) {
    int tt = r * 64 + lane;
    if (tt < NSAMPLE * 67) {
      int s = tt / 67;
      int f = tt - s * 67;
      int idx = list[wslot][s];
      float val;
      if (f < 3) {
        float cf = (f == 0) ? cqx : ((f == 1) ? cqy : cqz);
        val = xb[idx * 3 + f] - cf;
      } else {
        val = pb[(size_t)idx * C_FEAT + (f - 3)];
      }
      oq[tt] = val;
    }
  }
}

extern "C" void kernel_launch(void* const* d_in, const int* in_sizes, int n_in,
                              void* d_out, int out_size, void* d_ws, size_t ws_size,
                              hipStream_t stream) {
  const float* xyz = (const float*)d_in[0];
  const float* points = (const float*)d_in[1];
  float* out = (float*)d_out;
  float* new_xyz = out;
  float* new_points = out + (size_t)N_BATCH * NPOINT * 3;

  fps_kernel<<<N_BATCH, FPS_T, 0, stream>>>(xyz, new_xyz);
  ball_group_kernel<<<(N_BATCH * NPOINT) / 4, 256, 0, stream>>>(xyz, points, new_xyz, new_points);
}

// Round 8
// 1374.190 us; speedup vs baseline: 1.3812x; 1.2249x over previous
//
#include <hip/hip_runtime.h>
#include <cstdint>

#define N_PTS   8192
#define N_BATCH 8
#define NPOINT  2048
#define NSAMPLE 32
#define C_FEAT  64
#define R2      0.04f
#define FPS_T   1024
#define CH      (N_PTS / FPS_T)   // 8 points per thread = one chunk
#define NBINS   512               // 9-bit morton (3 bits/axis)
#define NWAVE   (FPS_T / 64)      // 16

static __device__ __forceinline__ uint32_t spread3(uint32_t v) {
  return (v & 1u) | ((v & 2u) << 2) | ((v & 4u) << 4);
}

static __device__ __forceinline__ uint32_t cell_of(float x, float y, float z) {
  int ix = (int)(x * 8.0f); ix = ix < 0 ? 0 : (ix > 7 ? 7 : ix);
  int iy = (int)(y * 8.0f); iy = iy < 0 ? 0 : (iy > 7 ? 7 : iy);
  int iz = (int)(z * 8.0f); iz = iz < 0 ? 0 : (iz > 7 ? 7 : iz);
  return spread3((uint32_t)ix) | (spread3((uint32_t)iy) << 1) | (spread3((uint32_t)iz) << 2);
}

// Wave-max step on packed positive f64 key via DPP (validated R2/R3/R6/R7).
#define DPP_MAXD(v, CTRL) do {                                                          \
  uint64_t u_ = __builtin_bit_cast(uint64_t, v);                                        \
  int lo_ = __builtin_amdgcn_update_dpp(0, (int)(uint32_t)u_,         CTRL, 0xF, 0xF, true); \
  int hi_ = __builtin_amdgcn_update_dpp(0, (int)(uint32_t)(u_ >> 32), CTRL, 0xF, 0xF, true); \
  double p_ = __builtin_bit_cast(double, ((uint64_t)(uint32_t)hi_ << 32) | (uint64_t)(uint32_t)lo_); \
  v = __builtin_fmax(v, p_);                                                            \
} while (0)

// ---------------------------------------------------------------------------
// FPS, one block per batch. R7's verified structure (f32 dist state, fmax
// tree + first-occurrence tie scan, DPP f64 key reduce, parity slots, exact
// bbox pruning) with two issue cuts:
//  (1) wave-level skip: if no lane in the wave updated its chunk (ballot==0),
//      the wave's cached reduced key (lane 63) is exact -> skip update + the
//      6-step DPP chain, republish cached key into the current parity slot.
//  (2) lane-parallel cross-wave reduce: ONE ds_read_b64 (slot lane&15) +
//      4-step DPP row-reduce + readlane(15), replacing 16 ds_read_b64 + a
//      15-op scalar f64 tree. Same f64 max over same keys -> identical far.
// ---------------------------------------------------------------------------
__global__ __launch_bounds__(FPS_T) void fps_kernel(const float* __restrict__ xyz,
                                                    float* __restrict__ new_xyz) {
  __shared__ float sx[N_PTS], sy[N_PTS], sz[N_PTS];
  __shared__ int perm[N_PTS];          // setup only; reused as cent[] in loop
  __shared__ uint32_t bins[NBINS];
  __shared__ double pkey[2][NWAVE];
  float* cent = (float*)perm;          // [NPOINT*3] = 24 KB < 32 KB

  const int b = blockIdx.x;
  const int t = threadIdx.x;
  const int lane = t & 63;
  const int w = t >> 6;
  const float* xb = xyz + (size_t)b * N_PTS * 3;

  // ---- setup: stage coords ----
  for (int e = t; e < N_PTS * 3; e += FPS_T) {
    float v = xb[e];
    int p = e / 3, c = e - 3 * p;
    if (c == 0) sx[p] = v;
    else if (c == 1) sy[p] = v;
    else sz[p] = v;
  }
  if (t < NBINS) bins[t] = 0;
  __syncthreads();

  // ---- counting sort by morton cell: histogram ----
#pragma unroll
  for (int k = 0; k < CH; ++k) {
    int p = k * FPS_T + t;
    atomicAdd(&bins[cell_of(sx[p], sy[p], sz[p])], 1u);
  }
  __syncthreads();

  // ---- exclusive scan of 512 bins (wave 0, in place) ----
  if (t < 64) {
    uint32_t v[8], e[8], run = 0;
#pragma unroll
    for (int j = 0; j < 8; ++j) v[j] = bins[t * 8 + j];
#pragma unroll
    for (int j = 0; j < 8; ++j) { e[j] = run; run += v[j]; }
    uint32_t inc = run;
#pragma unroll
    for (int off = 1; off < 64; off <<= 1) {
      uint32_t o = __shfl_up(inc, off, 64);
      if (t >= off) inc += o;
    }
    uint32_t base = inc - run;
#pragma unroll
    for (int j = 0; j < 8; ++j) bins[t * 8 + j] = base + e[j];
  }
  __syncthreads();

  // ---- scatter permutation ----
#pragma unroll
  for (int k = 0; k < CH; ++k) {
    int p = k * FPS_T + t;
    uint32_t pos = atomicAdd(&bins[cell_of(sx[p], sy[p], sz[p])], 1u);
    perm[pos] = p;
  }
  __syncthreads();

  // ---- load chunk into registers, compute bbox ----
  float rx[CH], ry[CH], rz[CH], dist[CH];
  uint32_t ridx[CH];
#pragma unroll
  for (int j = 0; j < CH; ++j) {
    int p = perm[CH * t + j];
    ridx[j] = (uint32_t)p;
    rx[j] = sx[p]; ry[j] = sy[p]; rz[j] = sz[p];
    dist[j] = __builtin_inff();
  }
  float bnx = rx[0], bxx = rx[0], bny = ry[0], bxy = ry[0], bnz = rz[0], bxz = rz[0];
#pragma unroll
  for (int j = 1; j < CH; ++j) {
    bnx = fminf(bnx, rx[j]); bxx = fmaxf(bxx, rx[j]);
    bny = fminf(bny, ry[j]); bxy = fmaxf(bxy, ry[j]);
    bnz = fminf(bnz, rz[j]); bxz = fmaxf(bxz, rz[j]);
  }
  __syncthreads();   // perm fully consumed; cent alias is now safe

  float cmax = __builtin_inff();   // chunk max dist (cached)
  uint32_t cidx = 0;               // chunk argmax orig idx (cached)
  double wkey = 0.0;               // cached wave-reduced key (lane 63 valid)
  int far = 0;

  for (int it = 0; it < NPOINT; ++it) {
    float cx = sx[far], cy = sy[far], cz = sz[far];
    if (t == 0) {   // LDS staging only -- no global store in the loop
      cent[it * 3 + 0] = cx;
      cent[it * 3 + 1] = cy;
      cent[it * 3 + 2] = cz;
    }

    // conservative lower bound of any d2 in this chunk (margin 1e-5 >> fp err)
    float gx = fmaxf(fmaxf(bnx - cx, cx - bxx), 0.0f);
    float gy = fmaxf(fmaxf(bny - cy, cy - bxy), 0.0f);
    float gz = fmaxf(fmaxf(bnz - cz, cz - bxz), 0.0f);
    float lb = gx * gx + gy * gy + gz * gz;

    bool act = !(lb * 0.99999f >= cmax);
    uint64_t am = __ballot(act);
    if (am != 0) {     // wave-uniform: some lane's cached key changes
      if (act) {
        {
#pragma clang fp contract(off)
#pragma unroll
          for (int j = 0; j < CH; ++j) {
            float dx = rx[j] - cx;
            float a = dx * dx;
            float dy = ry[j] - cy;
            a = a + dy * dy;         // exact left-to-right, no FMA
            float dz = rz[j] - cz;
            a = a + dz * dz;
            dist[j] = fminf(dist[j], a);
          }
        }
        // chunk max (tree) + first-occurrence (min orig idx) tie resolution
        float m0 = fmaxf(dist[0], dist[1]), m1 = fmaxf(dist[2], dist[3]);
        float m2 = fmaxf(dist[4], dist[5]), m3 = fmaxf(dist[6], dist[7]);
        cmax = fmaxf(fmaxf(m0, m1), fmaxf(m2, m3));
        uint32_t mi = 0xFFFFFFFFu;
#pragma unroll
        for (int j = 0; j < CH; ++j) {
          uint32_t cand = ridx[j] < mi ? ridx[j] : mi;
          mi = (dist[j] == cmax) ? cand : mi;
        }
        cidx = mi;
      }
      // wave reduce over ALL lanes' cached keys (active lanes just updated)
      double key = __builtin_bit_cast(double,
          ((uint64_t)__builtin_bit_cast(uint32_t, cmax) << 32) |
          (uint64_t)(0xFFFFFFFFu - cidx));
      DPP_MAXD(key, 0x111);   // row_shr 1
      DPP_MAXD(key, 0x112);   // row_shr 2
      DPP_MAXD(key, 0x114);   // row_shr 4
      DPP_MAXD(key, 0x118);   // row_shr 8
      DPP_MAXD(key, 0x142);   // row_bcast 15
      DPP_MAXD(key, 0x143);   // row_bcast 31  -> lane 63 has wave max
      wkey = key;             // cache (lane 63's copy is the wave max)
    }
    if (lane == 63) pkey[it & 1][w] = wkey;
    __syncthreads();

    // lane-parallel cross-wave reduce: lane reads slot (lane&15); 4-step DPP
    // row-reduce puts the max of all 16 slots in lane 15 of every row.
    double g = pkey[it & 1][lane & 15];
    DPP_MAXD(g, 0x111);
    DPP_MAXD(g, 0x112);
    DPP_MAXD(g, 0x114);
    DPP_MAXD(g, 0x118);
    uint64_t gu = __builtin_bit_cast(uint64_t, g);
    uint32_t glo = (uint32_t)__builtin_amdgcn_readlane((int)(uint32_t)gu, 15);
    far = (int)(0xFFFFFFFFu - glo);
  }

  // ---- one-time coalesced copy-out of staged centroids ----
  __syncthreads();
  float* ob = new_xyz + (size_t)b * NPOINT * 3;
  for (int e = t; e < NPOINT * 3; e += FPS_T) ob[e] = cent[e];
}

// ---------------------------------------------------------------------------
// Ball query + gather + concat, one wave per query (unchanged, verified).
// ---------------------------------------------------------------------------
__global__ __launch_bounds__(256) void ball_group_kernel(const float* __restrict__ xyz,
                                                         const float* __restrict__ points,
                                                         const float* __restrict__ new_xyz,
                                                         float* __restrict__ out_np) {
  __shared__ int list[4][NSAMPLE];
  const int wslot = threadIdx.x >> 6;
  const int lane = threadIdx.x & 63;
  const int qg = blockIdx.x * 4 + wslot;
  const int b = qg >> 11;

  const float* xb = xyz + (size_t)b * N_PTS * 3;
  const float* nq = new_xyz + (size_t)qg * 3;
  const float cqx = nq[0], cqy = nq[1], cqz = nq[2];

  int K = 0;
  {
#pragma clang fp contract(off)
    for (int c = 0; c < N_PTS / 64; ++c) {
      const int pt = c * 64 + lane;
      const float* p = xb + pt * 3;
      float dx = cqx - p[0];
      float dy = cqy - p[1];
      float dz = cqz - p[2];
      float d2 = dx * dx;
      d2 = d2 + dy * dy;
      d2 = d2 + dz * dz;
      bool in = d2 < R2;
      unsigned long long mask = __ballot(in);
      if (in) {
        int rank = __builtin_amdgcn_mbcnt_hi((uint32_t)(mask >> 32),
                     __builtin_amdgcn_mbcnt_lo((uint32_t)mask, 0));
        int s = K + rank;
        if (s < NSAMPLE) list[wslot][s] = pt;
      }
      K += (int)__popcll(mask);
      if (K >= NSAMPLE) break;   // wave-uniform
    }
  }
  __builtin_amdgcn_wave_barrier();
  int Kc = K < NSAMPLE ? K : NSAMPLE;
  int first = list[wslot][0];
  if (lane >= Kc && lane < NSAMPLE) list[wslot][lane] = first;
  __builtin_amdgcn_wave_barrier();

  const float* pb = points + (size_t)b * N_PTS * C_FEAT;
  float* oq = out_np + (size_t)qg * (NSAMPLE * 67);
  for (int r = 0; r < 34; ++r) {
    int tt = r * 64 + lane;
    if (tt < NSAMPLE * 67) {
      int s = tt / 67;
      int f = tt - s * 67;
      int idx = list[wslot][s];
      float val;
      if (f < 3) {
        float cf = (f == 0) ? cqx : ((f == 1) ? cqy : cqz);
        val = xb[idx * 3 + f] - cf;
      } else {
        val = pb[(size_t)idx * C_FEAT + (f - 3)];
      }
      oq[tt] = val;
    }
  }
}

extern "C" void kernel_launch(void* const* d_in, const int* in_sizes, int n_in,
                              void* d_out, int out_size, void* d_ws, size_t ws_size,
                              hipStream_t stream) {
  const float* xyz = (const float*)d_in[0];
  const float* points = (const float*)d_in[1];
  float* out = (float*)d_out;
  float* new_xyz = out;
  float* new_points = out + (size_t)N_BATCH * NPOINT * 3;

  fps_kernel<<<N_BATCH, FPS_T, 0, stream>>>(xyz, new_xyz);
  ball_group_kernel<<<(N_BATCH * NPOINT) / 4, 256, 0, stream>>>(xyz, points, new_xyz, new_points);
}